// Round 1
// baseline (691.186 us; speedup 1.0000x reference)
//
#include <hip/hip_runtime.h>
#include <math.h>

// InfoNCE loss: B=4096 rows, N=127 negatives, D=256, fp32.
// Kernel 1: one block per row -> per-row loss into d_ws.
// Kernel 2: mean over 4096 row losses -> d_out[0].

namespace {
constexpr int B = 4096;
constexpr int N = 127;
constexpr int D = 256;
constexpr float INV_TEMP = 1.0f / 0.07f;
constexpr float EPS = 1e-12f;

__device__ __forceinline__ float wave_reduce_sum(float v) {
    #pragma unroll
    for (int off = 32; off > 0; off >>= 1) v += __shfl_xor(v, off, 64);
    return v;
}

__device__ __forceinline__ float wave_reduce_max(float v) {
    #pragma unroll
    for (int off = 32; off > 0; off >>= 1) v = fmaxf(v, __shfl_xor(v, off, 64));
    return v;
}
} // namespace

__global__ __launch_bounds__(256) void infonce_rows(
    const float* __restrict__ anchor,
    const float* __restrict__ positive,
    const float* __restrict__ negatives,
    float* __restrict__ row_loss)
{
    const int b    = blockIdx.x;
    const int tid  = threadIdx.x;
    const int wave = tid >> 6;
    const int lane = tid & 63;

    __shared__ float scores[1 + N]; // [0]=pos score, [1+j]=neg j (raw cosine)

    // --- anchor fragment: lane holds a[b][lane*4 .. lane*4+3] ---
    const float4 a4 = *reinterpret_cast<const float4*>(
        anchor + (size_t)b * D + lane * 4);
    float asq = a4.x * a4.x + a4.y * a4.y + a4.z * a4.z + a4.w * a4.w;
    asq = wave_reduce_sum(asq);
    const float ainv = 1.0f / fmaxf(sqrtf(asq), EPS);
    const float4 ah = make_float4(a4.x * ainv, a4.y * ainv,
                                  a4.z * ainv, a4.w * ainv);

    // --- positive (wave 0 only) ---
    if (wave == 0) {
        const float4 p4 = *reinterpret_cast<const float4*>(
            positive + (size_t)b * D + lane * 4);
        float psq  = p4.x * p4.x + p4.y * p4.y + p4.z * p4.z + p4.w * p4.w;
        float pdot = ah.x * p4.x + ah.y * p4.y + ah.z * p4.z + ah.w * p4.w;
        psq  = wave_reduce_sum(psq);
        pdot = wave_reduce_sum(pdot);
        if (lane == 0)
            scores[0] = pdot / fmaxf(sqrtf(psq), EPS);
    }

    // --- negatives: wave w takes j = w, w+4, ... ---
    const float* nrow_base = negatives + (size_t)b * N * D;
    for (int j = wave; j < N; j += 4) {
        const float4 n4 = *reinterpret_cast<const float4*>(
            nrow_base + (size_t)j * D + lane * 4);
        float nsq  = n4.x * n4.x + n4.y * n4.y + n4.z * n4.z + n4.w * n4.w;
        float ndot = ah.x * n4.x + ah.y * n4.y + ah.z * n4.z + ah.w * n4.w;
        nsq  = wave_reduce_sum(nsq);
        ndot = wave_reduce_sum(ndot);
        if (lane == 0)
            scores[1 + j] = ndot / fmaxf(sqrtf(nsq), EPS);
    }
    __syncthreads();

    // --- logsumexp over 128 logits (wave 0) ---
    if (wave == 0) {
        const float s0 = scores[lane]      * INV_TEMP;
        const float s1 = scores[lane + 64] * INV_TEMP;
        float m = wave_reduce_max(fmaxf(s0, s1));
        float e = expf(s0 - m) + expf(s1 - m);
        e = wave_reduce_sum(e);
        if (lane == 0)
            row_loss[b] = m + logf(e) - scores[0] * INV_TEMP;
    }
}

__global__ __launch_bounds__(256) void reduce_mean(
    const float* __restrict__ row_loss, float* __restrict__ out)
{
    __shared__ float wsum[4];
    const int tid  = threadIdx.x;
    const int wave = tid >> 6;
    const int lane = tid & 63;

    float s = 0.0f;
    for (int i = tid; i < B; i += 256) s += row_loss[i];
    s = wave_reduce_sum(s);
    if (lane == 0) wsum[wave] = s;
    __syncthreads();
    if (tid == 0)
        out[0] = (wsum[0] + wsum[1] + wsum[2] + wsum[3]) * (1.0f / (float)B);
}

extern "C" void kernel_launch(void* const* d_in, const int* in_sizes, int n_in,
                              void* d_out, int out_size, void* d_ws, size_t ws_size,
                              hipStream_t stream) {
    const float* anchor    = (const float*)d_in[0];
    const float* positive  = (const float*)d_in[1];
    const float* negatives = (const float*)d_in[2];
    float* out      = (float*)d_out;
    float* row_loss = (float*)d_ws;   // B floats = 16 KB scratch

    infonce_rows<<<B, 256, 0, stream>>>(anchor, positive, negatives, row_loss);
    reduce_mean<<<1, 256, 0, stream>>>(row_loss, out);
}

// Round 2
// 681.399 us; speedup vs baseline: 1.0144x; 1.0144x over previous
//
#include <hip/hip_runtime.h>
#include <math.h>

// InfoNCE loss: B=4096 rows, N=127 negatives, D=256, fp32.
// Kernel 1: one block (256 thr = 16 groups of 16 lanes) per row.
//   Vector v in [0,128): v=0 -> positive, v>=1 -> negative v-1.
//   Group g scores vectors v = g + 16*it, it=0..7. 16 lanes x 4 float4
//   chunks cover D=256. Reductions are 4-step xor-shuffles that stay
//   inside each 16-lane group, so all 4 groups of a wave reduce
//   simultaneously with one instruction stream. Next vector's loads are
//   issued before the current reduction (double buffer) for MLP.
// Kernel 2: mean over 4096 row losses -> d_out[0].

namespace {
constexpr int B = 4096;
constexpr int N = 127;
constexpr int D = 256;
constexpr int V = N + 1;  // 128 scored vectors per row
constexpr float INV_TEMP = 1.0f / 0.07f;
constexpr float EPS = 1e-12f;

__device__ __forceinline__ float group16_reduce_sum(float v) {
    #pragma unroll
    for (int off = 1; off < 16; off <<= 1) v += __shfl_xor(v, off, 64);
    return v;
}
__device__ __forceinline__ float wave_reduce_sum(float v) {
    #pragma unroll
    for (int off = 32; off > 0; off >>= 1) v += __shfl_xor(v, off, 64);
    return v;
}
__device__ __forceinline__ float wave_reduce_max(float v) {
    #pragma unroll
    for (int off = 32; off > 0; off >>= 1) v = fmaxf(v, __shfl_xor(v, off, 64));
    return v;
}
} // namespace

__global__ __launch_bounds__(256) void infonce_rows(
    const float* __restrict__ anchor,
    const float* __restrict__ positive,
    const float* __restrict__ negatives,
    float* __restrict__ row_loss)
{
    const int b    = blockIdx.x;
    const int tid  = threadIdx.x;
    const int lane = tid & 63;
    const int sub  = lane & 15;   // lane within 16-group
    const int g    = tid >> 4;    // global 16-group id, 0..15

    __shared__ float scores[V];

    // --- anchor fragment: lane holds elements {i*64 + sub*4 .. +3}, i=0..3 ---
    const float* arow = anchor + (size_t)b * D;
    float4 aa[4];
    #pragma unroll
    for (int i = 0; i < 4; ++i)
        aa[i] = *reinterpret_cast<const float4*>(arow + i * 64 + sub * 4);
    float asq = 0.f;
    #pragma unroll
    for (int i = 0; i < 4; ++i)
        asq += aa[i].x*aa[i].x + aa[i].y*aa[i].y + aa[i].z*aa[i].z + aa[i].w*aa[i].w;
    asq = group16_reduce_sum(asq);  // 16 lanes x 16 elems = full 256-sum
    const float ainv = 1.0f / fmaxf(sqrtf(asq), EPS);
    #pragma unroll
    for (int i = 0; i < 4; ++i) {
        aa[i].x *= ainv; aa[i].y *= ainv; aa[i].z *= ainv; aa[i].w *= ainv;
    }

    auto vec_ptr = [&](int v) -> const float* {
        return (v == 0) ? (positive + (size_t)b * D)
                        : (negatives + ((size_t)b * N + (size_t)(v - 1)) * D);
    };

    // --- 8 vectors per group, double-buffered loads ---
    float4 cur[4];
    {
        const float* p = vec_ptr(g);
        #pragma unroll
        for (int i = 0; i < 4; ++i)
            cur[i] = *reinterpret_cast<const float4*>(p + i * 64 + sub * 4);
    }
    #pragma unroll
    for (int it = 0; it < 8; ++it) {
        float4 nxt[4];
        if (it < 7) {
            const float* p = vec_ptr(g + 16 * (it + 1));
            #pragma unroll
            for (int i = 0; i < 4; ++i)
                nxt[i] = *reinterpret_cast<const float4*>(p + i * 64 + sub * 4);
        }
        float ndot = 0.f, nsq = 0.f;
        #pragma unroll
        for (int i = 0; i < 4; ++i) {
            ndot += aa[i].x*cur[i].x + aa[i].y*cur[i].y
                  + aa[i].z*cur[i].z + aa[i].w*cur[i].w;
            nsq  += cur[i].x*cur[i].x + cur[i].y*cur[i].y
                  + cur[i].z*cur[i].z + cur[i].w*cur[i].w;
        }
        ndot = group16_reduce_sum(ndot);   // one instr stream reduces all 4 groups
        nsq  = group16_reduce_sum(nsq);
        if (sub == 0)
            scores[g + 16 * it] = ndot / fmaxf(sqrtf(nsq), EPS);
        #pragma unroll
        for (int i = 0; i < 4; ++i) cur[i] = nxt[i];
    }
    __syncthreads();

    // --- logsumexp over 128 logits (first wave) ---
    if (tid < 64) {
        const float s0 = scores[lane]      * INV_TEMP;
        const float s1 = scores[lane + 64] * INV_TEMP;
        float m = wave_reduce_max(fmaxf(s0, s1));
        float e = expf(s0 - m) + expf(s1 - m);
        e = wave_reduce_sum(e);
        if (lane == 0)
            row_loss[b] = m + logf(e) - scores[0] * INV_TEMP;
    }
}

__global__ __launch_bounds__(256) void reduce_mean(
    const float* __restrict__ row_loss, float* __restrict__ out)
{
    __shared__ float wsum[4];
    const int tid  = threadIdx.x;
    const int wave = tid >> 6;
    const int lane = tid & 63;

    float s = 0.0f;
    for (int i = tid; i < B; i += 256) s += row_loss[i];
    s = wave_reduce_sum(s);
    if (lane == 0) wsum[wave] = s;
    __syncthreads();
    if (tid == 0)
        out[0] = (wsum[0] + wsum[1] + wsum[2] + wsum[3]) * (1.0f / (float)B);
}

extern "C" void kernel_launch(void* const* d_in, const int* in_sizes, int n_in,
                              void* d_out, int out_size, void* d_ws, size_t ws_size,
                              hipStream_t stream) {
    const float* anchor    = (const float*)d_in[0];
    const float* positive  = (const float*)d_in[1];
    const float* negatives = (const float*)d_in[2];
    float* out      = (float*)d_out;
    float* row_loss = (float*)d_ws;   // B floats = 16 KB scratch

    infonce_rows<<<B, 256, 0, stream>>>(anchor, positive, negatives, row_loss);
    reduce_mean<<<1, 256, 0, stream>>>(row_loss, out);
}

// Round 3
// 646.601 us; speedup vs baseline: 1.0690x; 1.0538x over previous
//
#include <hip/hip_runtime.h>
#include <math.h>

// InfoNCE loss: B=4096 rows, N=127 negatives, D=256, fp32.
// R3: pure-streaming hot loop. One block per row; 16 groups x 16 lanes.
// Group g accumulates (dot, sumsq) for vectors v = g + 16*it, it=0..7,
// entirely in registers (no shuffles / LDS on the load path). All 16
// group-wise reductions happen once at the end. Streamed inputs use
// non-temporal loads (read-once, skip L2 retention).

namespace {
constexpr int B = 4096;
constexpr int N = 127;
constexpr int D = 256;
constexpr int V = N + 1;
constexpr float INV_TEMP = 1.0f / 0.07f;
constexpr float EPS = 1e-12f;

typedef float f32x4 __attribute__((ext_vector_type(4)));

__device__ __forceinline__ float group16_reduce_sum(float v) {
    #pragma unroll
    for (int off = 1; off < 16; off <<= 1) v += __shfl_xor(v, off, 64);
    return v;
}
__device__ __forceinline__ float wave_reduce_sum(float v) {
    #pragma unroll
    for (int off = 32; off > 0; off >>= 1) v += __shfl_xor(v, off, 64);
    return v;
}
__device__ __forceinline__ float wave_reduce_max(float v) {
    #pragma unroll
    for (int off = 32; off > 0; off >>= 1) v = fmaxf(v, __shfl_xor(v, off, 64));
    return v;
}
} // namespace

__global__ __launch_bounds__(256) void infonce_rows(
    const float* __restrict__ anchor,
    const float* __restrict__ positive,
    const float* __restrict__ negatives,
    float* __restrict__ row_loss)
{
    const int b   = blockIdx.x;
    const int tid = threadIdx.x;
    const int sub = tid & 15;   // lane within 16-group
    const int g   = tid >> 4;   // 16-group id, 0..15

    __shared__ float scores[V];

    // --- anchor fragment: lane holds elements {i*64 + sub*4 .. +3}, i=0..3 ---
    const float* arow = anchor + (size_t)b * D;
    f32x4 aa[4];
    #pragma unroll
    for (int i = 0; i < 4; ++i)
        aa[i] = *reinterpret_cast<const f32x4*>(arow + i * 64 + sub * 4);
    float asq = 0.f;
    #pragma unroll
    for (int i = 0; i < 4; ++i)
        asq += aa[i].x*aa[i].x + aa[i].y*aa[i].y + aa[i].z*aa[i].z + aa[i].w*aa[i].w;
    asq = group16_reduce_sum(asq);
    const float ainv = 1.0f / fmaxf(sqrtf(asq), EPS);
    #pragma unroll
    for (int i = 0; i < 4; ++i) aa[i] *= ainv;

    // --- streaming accumulation: 8 vectors per group, registers only ---
    float dot[8], sq[8];
    #pragma unroll
    for (int it = 0; it < 8; ++it) {
        const int v = g + 16 * it;
        const float* p = (v == 0)
            ? (positive + (size_t)b * D)
            : (negatives + ((size_t)b * N + (size_t)(v - 1)) * D);
        float d = 0.f, s = 0.f;
        #pragma unroll
        for (int i = 0; i < 4; ++i) {
            const f32x4 x = __builtin_nontemporal_load(
                reinterpret_cast<const f32x4*>(p + i * 64 + sub * 4));
            d += aa[i].x*x.x + aa[i].y*x.y + aa[i].z*x.z + aa[i].w*x.w;
            s += x.x*x.x + x.y*x.y + x.z*x.z + x.w*x.w;
        }
        dot[it] = d; sq[it] = s;
    }

    // --- batched group reductions (off the memory path) ---
    #pragma unroll
    for (int it = 0; it < 8; ++it) {
        const float d = group16_reduce_sum(dot[it]);
        const float s = group16_reduce_sum(sq[it]);
        if (sub == 0)
            scores[g + 16 * it] = d / fmaxf(sqrtf(s), EPS);
    }
    __syncthreads();

    // --- logsumexp over 128 logits (first wave) ---
    if (tid < 64) {
        const int lane = tid;
        const float s0 = scores[lane]      * INV_TEMP;
        const float s1 = scores[lane + 64] * INV_TEMP;
        float m = wave_reduce_max(fmaxf(s0, s1));
        float e = expf(s0 - m) + expf(s1 - m);
        e = wave_reduce_sum(e);
        if (lane == 0)
            row_loss[b] = m + logf(e) - scores[0] * INV_TEMP;
    }
}

__global__ __launch_bounds__(256) void reduce_mean(
    const float* __restrict__ row_loss, float* __restrict__ out)
{
    __shared__ float wsum[4];
    const int tid  = threadIdx.x;
    const int wave = tid >> 6;
    const int lane = tid & 63;

    float s = 0.0f;
    for (int i = tid; i < B; i += 256) s += row_loss[i];
    s = wave_reduce_sum(s);
    if (lane == 0) wsum[wave] = s;
    __syncthreads();
    if (tid == 0)
        out[0] = (wsum[0] + wsum[1] + wsum[2] + wsum[3]) * (1.0f / (float)B);
}

extern "C" void kernel_launch(void* const* d_in, const int* in_sizes, int n_in,
                              void* d_out, int out_size, void* d_ws, size_t ws_size,
                              hipStream_t stream) {
    const float* anchor    = (const float*)d_in[0];
    const float* positive  = (const float*)d_in[1];
    const float* negatives = (const float*)d_in[2];
    float* out      = (float*)d_out;
    float* row_loss = (float*)d_ws;   // B floats = 16 KB scratch

    infonce_rows<<<B, 256, 0, stream>>>(anchor, positive, negatives, row_loss);
    reduce_mean<<<1, 256, 0, stream>>>(row_loss, out);
}